// Round 18
// baseline (484.886 us; speedup 1.0000x reference)
//
#include <hip/hip_runtime.h>
#include <cstdint>

#define N_USERS 100000
#define N_ITEMS 50000
#define N_NODES (N_USERS + N_ITEMS)
#define EMB 64
#define N_EDGES 4000000
#define LN_EPS 1e-5f

#define NBKT 1172           // ceil(N_NODES/128): buckets of 128 rows
#define C_BLOCKS 1024
#define EPB 3907            // ceil(N_EDGES/C_BLOCKS)
#define ENC128_BLOCKS 1563  // (N_USERS+63)/64
#define ENC_ITEM_BLOCKS 782 // (N_ITEMS+63)/64
#define UPREP_BLOCKS 512

#define K1_TOTAL (C_BLOCKS + ENC128_BLOCKS)                       // 2587
#define K2_OTHER (2 * ENC_ITEM_BLOCKS + UPREP_BLOCKS)             // 2076
#define K2_TOTAL (NBKT + K2_OTHER)                                // 3248

// K1 smem: stage 31264 | cnt 4688 (@31264) | offA 4704 (@35952) | sums 1024 (@40656)
#define K1_SMEM 41728
// K2 smem: enc carve 17152 (gather needs only cnt/pos/sbk = 3072)
#define K2_SMEM 17408

__device__ __forceinline__ float b2f(unsigned short h) {
    return __uint_as_float((unsigned)h << 16);
}
__device__ __forceinline__ unsigned short f2b(float f) {
    unsigned u = __float_as_uint(f);
    u += 0x7FFFu + ((u >> 16) & 1u);   // RNE
    return (unsigned short)(u >> 16);
}
__device__ __forceinline__ uint2 pack4(float a, float b, float c, float d) {
    return make_uint2((unsigned)f2b(a) | ((unsigned)f2b(b) << 16),
                      (unsigned)f2b(c) | ((unsigned)f2b(d) << 16));
}

// ---------------------------------------------------------------------------
// f32 encoder body (runtime K) — R12-proven. smem carve: 8704|8192|256 = 17152
// WRITE_OUT=0: skip output, accumulate column sums into colsum[64].
// ---------------------------------------------------------------------------
template<int WRITE_OUT>
__device__ __forceinline__ void enc_body(
    int blk, char* smem, const float* __restrict__ X, const float* __restrict__ W,
    const float* __restrict__ bb, const float* __restrict__ gg,
    const float* __restrict__ be, float* __restrict__ out,
    float* __restrict__ colsum, int K, int R)
{
    float (*sXT)[68] = reinterpret_cast<float(*)[68]>(smem);
    float (*sW)[64] = reinterpret_cast<float(*)[64]>(smem + 8704);
    float* scs = reinterpret_cast<float*>(smem + 8704 + 8192);

    int tid = threadIdx.x;
    int tx = tid & 15;
    int ty = tid >> 4;
    int rbase = blk * 64;

    int xr = tid >> 2;
    int xc = (tid & 3) * 8;
    int wr = tid >> 3;
    int wc = (tid & 7) * 8;

    int gxrow = rbase + xr; if (gxrow >= R) gxrow = R - 1;
    const float* xsrc = X + (size_t)gxrow * K + xc;

    float4 bv = *reinterpret_cast<const float4*>(&bb[tx * 4]);
    float4 gv = *reinterpret_cast<const float4*>(&gg[tx * 4]);
    float4 bev = *reinterpret_cast<const float4*>(&be[tx * 4]);

    float acc[4][4];
    #pragma unroll
    for (int i = 0; i < 4; ++i) {
        acc[i][0] = bv.x; acc[i][1] = bv.y; acc[i][2] = bv.z; acc[i][3] = bv.w;
    }

    for (int kc = 0; kc < K; kc += 32) {
        float4 a0 = *reinterpret_cast<const float4*>(xsrc + kc);
        float4 a1 = *reinterpret_cast<const float4*>(xsrc + kc + 4);
        float4 w0 = *reinterpret_cast<const float4*>(&W[(size_t)(kc + wr) * EMB + wc]);
        float4 w1 = *reinterpret_cast<const float4*>(&W[(size_t)(kc + wr) * EMB + wc + 4]);
        __syncthreads();
        sXT[xc + 0][xr] = a0.x; sXT[xc + 1][xr] = a0.y;
        sXT[xc + 2][xr] = a0.z; sXT[xc + 3][xr] = a0.w;
        sXT[xc + 4][xr] = a1.x; sXT[xc + 5][xr] = a1.y;
        sXT[xc + 6][xr] = a1.z; sXT[xc + 7][xr] = a1.w;
        *reinterpret_cast<float4*>(&sW[wr][wc]) = w0;
        *reinterpret_cast<float4*>(&sW[wr][wc + 4]) = w1;
        __syncthreads();
        #pragma unroll
        for (int k = 0; k < 32; ++k) {
            float4 xv = *reinterpret_cast<const float4*>(&sXT[k][ty * 4]);
            float4 wv = *reinterpret_cast<const float4*>(&sW[k][tx * 4]);
            float xs[4] = {xv.x, xv.y, xv.z, xv.w};
            float wsv[4] = {wv.x, wv.y, wv.z, wv.w};
            #pragma unroll
            for (int i = 0; i < 4; ++i)
                #pragma unroll
                for (int j = 0; j < 4; ++j)
                    acc[i][j] = fmaf(xs[i], wsv[j], acc[i][j]);
        }
    }

    float gls[4] = {gv.x, gv.y, gv.z, gv.w};
    float bels[4] = {bev.x, bev.y, bev.z, bev.w};
    float csum[4] = {0.f, 0.f, 0.f, 0.f};
    #pragma unroll
    for (int i = 0; i < 4; ++i) {
        float s = acc[i][0] + acc[i][1] + acc[i][2] + acc[i][3];
        float q = acc[i][0]*acc[i][0] + acc[i][1]*acc[i][1]
                + acc[i][2]*acc[i][2] + acc[i][3]*acc[i][3];
        #pragma unroll
        for (int off = 1; off < 16; off <<= 1) {
            s += __shfl_xor(s, off, 64);
            q += __shfl_xor(q, off, 64);
        }
        float mu = s * (1.f / EMB);
        float var = q * (1.f / EMB) - mu * mu;
        float rs = rsqrtf(var + LN_EPS);
        int row = rbase + ty * 4 + i;
        bool valid = row < R;
        float t[4];
        #pragma unroll
        for (int j = 0; j < 4; ++j) {
            float v = (acc[i][j] - mu) * rs * gls[j] + bels[j];
            t[j] = v > 0.f ? v : 0.2f * v;
        }
        if (WRITE_OUT) {
            if (valid)
                *reinterpret_cast<float4*>(&out[(size_t)row * EMB + tx * 4]) =
                    make_float4(t[0], t[1], t[2], t[3]);
        } else {
            #pragma unroll
            for (int j = 0; j < 4; ++j) csum[j] += valid ? t[j] : 0.f;
        }
    }

    if (!WRITE_OUT) {
        #pragma unroll
        for (int j = 0; j < 4; ++j) {
            csum[j] += __shfl_xor(csum[j], 16, 64);
            csum[j] += __shfl_xor(csum[j], 32, 64);
        }
        if (tid < 64) scs[tid] = 0.f;
        __syncthreads();
        if ((tid & 63) < 16) {
            #pragma unroll
            for (int j = 0; j < 4; ++j) atomicAdd(&scs[tx * 4 + j], csum[j]);
        }
        __syncthreads();
        if (tid < 64) unsafeAtomicAdd(&colsum[tid], scs[tid]);
    }
}

// ---------------------------------------------------------------------------
// scatter_sort body: per-block LDS counting sort over 128-row buckets.
// ---------------------------------------------------------------------------
__device__ __forceinline__ void scatter_sort_body(
    int blk, char* smem, const int* __restrict__ rows,
    const int* __restrict__ cols, const float* __restrict__ vals,
    int* __restrict__ bktcnt, int* __restrict__ hmatT, int2* __restrict__ tmp)
{
    int2* stage = reinterpret_cast<int2*>(smem);
    int* cnt  = reinterpret_cast<int*>(smem + 31264);
    int* offA = reinterpret_cast<int*>(smem + 35952);
    int* sums = reinterpret_cast<int*>(smem + 40656);

    int tid = threadIdx.x;
    int s = blk * EPB;
    int e = s + EPB; if (e > N_EDGES) e = N_EDGES;
    int n = e - s;

    for (int i = tid; i < NBKT; i += 256) cnt[i] = 0;
    __syncthreads();
    for (int i = s + tid; i < e; i += 256)
        atomicAdd(&cnt[rows[i] >> 7], 1);
    __syncthreads();

    int base = tid * 5;
    int loc[5]; int run = 0;
    #pragma unroll
    for (int j = 0; j < 5; ++j) {
        int idx = base + j;
        int v = (idx < NBKT) ? cnt[idx] : 0;
        loc[j] = run; run += v;
    }
    sums[tid] = run;
    __syncthreads();
    for (int off = 1; off < 256; off <<= 1) {
        int u = (tid >= off) ? sums[tid - off] : 0;
        __syncthreads();
        sums[tid] += u;
        __syncthreads();
    }
    int excl = tid ? sums[tid - 1] : 0;
    #pragma unroll
    for (int j = 0; j < 5; ++j) {
        int idx = base + j;
        if (idx < NBKT) offA[idx] = excl + loc[j];
    }
    if (tid == 0) offA[NBKT] = n;
    __syncthreads();

    for (int i = tid; i < NBKT; i += 256) {
        if (cnt[i]) atomicAdd(&bktcnt[i], cnt[i]);
        cnt[i] = offA[i];
    }
    for (int i = tid; i <= NBKT; i += 256)
        hmatT[(size_t)i * C_BLOCKS + blk] = offA[i];
    __syncthreads();

    for (int i = s + tid; i < e; i += 256) {
        int r = rows[i];
        int p = atomicAdd(&cnt[r >> 7], 1);
        stage[p] = make_int2(cols[i] | ((r & 127) << 18), __float_as_int(vals[i]));
    }
    __syncthreads();

    int2* dst = tmp + (size_t)blk * EPB;
    for (int i = tid; i < n; i += 256) dst[i] = stage[i];
}

// ---------------------------------------------------------------------------
// gather body (stage-less): bucket-per-block (128 rows). Own global prefix,
// pass1 count -> scan -> offs[]; pass2 writes edges[] DIRECTLY at absolute
// positions (per-row monotone pointers; ~8KB active L2 window per block).
// LDS: cnt/pos/sbk = 3KB only -> kernel runs at enc occupancy (9 blocks/CU).
// ---------------------------------------------------------------------------
__device__ __forceinline__ void gather_body(
    int b, char* smem, const int2* __restrict__ tmp,
    const int* __restrict__ hmatT, const int* __restrict__ bktcnt,
    int* __restrict__ offs, int2* __restrict__ edges)
{
    int* cnt = reinterpret_cast<int*>(smem);
    int* pos = reinterpret_cast<int*>(smem + 1024);
    int* sbk = reinterpret_cast<int*>(smem + 2048);
    int t = threadIdx.x;

    int base = t * 5, part = 0;
    #pragma unroll
    for (int j = 0; j < 5; ++j) {
        int idx = base + j;
        if (idx < b) part += bktcnt[idx];
    }
    sbk[t] = part;
    cnt[t] = 0;
    __syncthreads();
    for (int off = 1; off < 256; off <<= 1) {
        int u = (t >= off) ? sbk[t - off] : 0;
        __syncthreads();
        sbk[t] += u;
        __syncthreads();
    }
    int gb = sbk[255];

    const int* h0 = hmatT + (size_t)b * C_BLOCKS;
    const int* h1 = hmatT + (size_t)(b + 1) * C_BLOCKS;

    // pass 1: count rows across all runs
    for (int blk = t; blk < C_BLOCKS; blk += 256) {
        int st = h0[blk], en = h1[blk];
        const int2* src = tmp + (size_t)blk * EPB;
        for (int i = st; i < en; ++i)
            atomicAdd(&cnt[(src[i].x >> 18) & 127], 1);
    }
    __syncthreads();

    int v = cnt[t];
    __syncthreads();
    for (int off = 1; off < 256; off <<= 1) {
        int u = (t >= off) ? cnt[t - off] : 0;
        __syncthreads();
        cnt[t] += u;
        __syncthreads();
    }
    int incl = cnt[t];
    int row = (b << 7) + t;
    if (t < 128 && row < N_NODES) offs[row] = gb + incl;
    pos[t] = gb + incl - v;    // ABSOLUTE start of this row's segment
    __syncthreads();

    // pass 2: write records directly to edges[] at absolute positions
    for (int blk = t; blk < C_BLOCKS; blk += 256) {
        int st = h0[blk], en = h1[blk];
        const int2* src = tmp + (size_t)blk * EPB;
        for (int i = st; i < en; ++i) {
            int2 ed = src[i];
            int p = atomicAdd(&pos[(ed.x >> 18) & 127], 1);
            edges[p] = make_int2(ed.x & 0x3FFFF, ed.y);
        }
    }
}

// ---------------------------------------------------------------------------
// user prep body: e0b (bf16 mirror only) + column-sum to hdr.
// ---------------------------------------------------------------------------
__device__ __forceinline__ void user_prep_body(
    int bid, int nblk, char* smem, const float* __restrict__ U,
    unsigned short* __restrict__ e0b, float* __restrict__ sum)
{
    float* scs = reinterpret_cast<float*>(smem);
    int tid = threadIdx.x;
    int lane = tid & 63;
    const int n4 = N_USERS * EMB / 4;
    int stride = nblk * 256;
    const float4* A = reinterpret_cast<const float4*>(U);
    uint2* OB = reinterpret_cast<uint2*>(e0b);
    float c0 = 0.f, c1 = 0.f, c2 = 0.f, c3 = 0.f;
    for (int i = bid * 256 + tid; i < n4; i += stride) {
        float4 v = A[i];
        OB[i] = pack4(v.x, v.y, v.z, v.w);
        c0 += v.x; c1 += v.y; c2 += v.z; c3 += v.w;
    }
    c0 += __shfl_xor(c0, 16, 64); c0 += __shfl_xor(c0, 32, 64);
    c1 += __shfl_xor(c1, 16, 64); c1 += __shfl_xor(c1, 32, 64);
    c2 += __shfl_xor(c2, 16, 64); c2 += __shfl_xor(c2, 32, 64);
    c3 += __shfl_xor(c3, 16, 64); c3 += __shfl_xor(c3, 32, 64);
    if (tid < 64) scs[tid] = 0.f;
    __syncthreads();
    if (lane < 16) {
        atomicAdd(&scs[lane * 4 + 0], c0);
        atomicAdd(&scs[lane * 4 + 1], c1);
        atomicAdd(&scs[lane * 4 + 2], c2);
        atomicAdd(&scs[lane * 4 + 3], c3);
    }
    __syncthreads();
    if (tid < 64) unsafeAtomicAdd(&sum[tid], scs[tid]);
}

// ---------------------------------------------------------------------------
// K1: scatter_sort || enc128-colsum, Bresenham-interleaved.
// ---------------------------------------------------------------------------
__global__ __launch_bounds__(256) void k1_kernel(
    const int* __restrict__ rows, const int* __restrict__ cols,
    const float* __restrict__ vals, int* __restrict__ bktcnt,
    int* __restrict__ hmatT, int2* __restrict__ tmp,
    const float* __restrict__ mf2, const float* __restrict__ W2,
    const float* __restrict__ b2v, const float* __restrict__ g2,
    const float* __restrict__ be2, float* __restrict__ hdr)
{
    extern __shared__ char smem[];
    unsigned bid = blockIdx.x;
    unsigned c  = (bid * (unsigned)C_BLOCKS) / (unsigned)K1_TOTAL;
    unsigned c1 = ((bid + 1) * (unsigned)C_BLOCKS) / (unsigned)K1_TOTAL;
    if (c1 > c)
        scatter_sort_body((int)c, smem, rows, cols, vals, bktcnt, hmatT, tmp);
    else
        enc_body<0>((int)(bid - c), smem, mf2, W2, b2v, g2, be2,
                    nullptr, hdr + 64, 128, N_USERS);
}

// ---------------------------------------------------------------------------
// K2: gather || enc768 || enc384 || user_prep, Bresenham-interleaved.
// Uniform lean smem (17.4KB) -> ~9 blocks/CU for all roles.
// ---------------------------------------------------------------------------
__global__ __launch_bounds__(256) void k2_kernel(
    const int2* __restrict__ tmp, const int* __restrict__ hmatT,
    const int* __restrict__ bktcnt, int* __restrict__ offs,
    int2* __restrict__ edges,
    const float* __restrict__ mf0, const float* __restrict__ W0,
    const float* __restrict__ b0v, const float* __restrict__ g0,
    const float* __restrict__ be0, float* __restrict__ m0b,
    const float* __restrict__ mf1, const float* __restrict__ W1,
    const float* __restrict__ b1v, const float* __restrict__ g1,
    const float* __restrict__ be1, float* __restrict__ m1b,
    const float* __restrict__ U, unsigned short* __restrict__ e0b,
    float* __restrict__ hdr)
{
    extern __shared__ char smem[];
    unsigned bid = blockIdx.x;
    unsigned c  = (bid * (unsigned)NBKT) / (unsigned)K2_TOTAL;
    unsigned c1 = ((bid + 1) * (unsigned)NBKT) / (unsigned)K2_TOTAL;
    if (c1 > c) {
        gather_body((int)c, smem, tmp, hmatT, bktcnt, offs, edges);
        return;
    }
    int o = (int)(bid - c);   // 0..K2_OTHER-1
    if (o < ENC_ITEM_BLOCKS)
        enc_body<1>(o, smem, mf0, W0, b0v, g0, be0, m0b, nullptr, 768, N_ITEMS);
    else if (o < 2 * ENC_ITEM_BLOCKS)
        enc_body<1>(o - ENC_ITEM_BLOCKS, smem, mf1, W1, b1v, g1, be1,
                    m1b, nullptr, 384, N_ITEMS);
    else
        user_prep_body(o - 2 * ENC_ITEM_BLOCKS, UPREP_BLOCKS, smem, U, e0b, hdr);
}

// hdr: [0:64) u_sum [64:128) um_sum [128:192) u_mean [192:256) m2_vec [256:320) pre1
__global__ void finalize_kernel(const float* __restrict__ aW1,
                                const float* __restrict__ ab1,
                                float* __restrict__ hdr)
{
    int d = threadIdx.x; // 64 threads
    float um = hdr[d] * (1.f / N_USERS);
    float m2 = hdr[64 + d] * (1.f / N_USERS);
    hdr[128 + d] = um;
    hdr[192 + d] = m2;
    float acc = ab1[d];
    for (int k = 0; k < EMB; ++k)
        acc = fmaf(hdr[k] * (1.f / N_USERS), aW1[k * EMB + d], acc);
    hdr[256 + d] = acc;
}

// ---------------------------------------------------------------------------
// Blocked item fuse: 64 items per 256-thread block; writes e0b (bf16) only.
// ---------------------------------------------------------------------------
__global__ __launch_bounds__(256) void item_fuse_gemm_kernel(
    const float* __restrict__ item_emb, const float* __restrict__ m0,
    const float* __restrict__ m1, const float* __restrict__ hdr,
    const float* __restrict__ aW1, const float* __restrict__ aW2,
    const float* __restrict__ ab2, unsigned short* __restrict__ e0b)
{
    __shared__ float sIE[64][68];   // [k][row] transposed item tile (+4 pad)
    __shared__ float sW1[64][64];   // [k][col] = aW1[64+k][col]

    int tid = threadIdx.x;
    int tx = tid & 15;
    int ty = tid >> 4;
    int rbase = blockIdx.x * 64;

    int lr = tid >> 2;              // 0..63
    int lc = (tid & 3) * 16;        // 0,16,32,48
    int grow = rbase + lr; if (grow >= N_ITEMS) grow = N_ITEMS - 1;
    const float4* ier = reinterpret_cast<const float4*>(item_emb + (size_t)grow * EMB + lc);
    const float4* wsrc = reinterpret_cast<const float4*>(aW1 + (size_t)(64 + lr) * EMB + lc);
    #pragma unroll
    for (int q = 0; q < 4; ++q) {
        float4 v = ier[q];
        sIE[lc + q*4 + 0][lr] = v.x; sIE[lc + q*4 + 1][lr] = v.y;
        sIE[lc + q*4 + 2][lr] = v.z; sIE[lc + q*4 + 3][lr] = v.w;
        *reinterpret_cast<float4*>(&sW1[lr][lc + q*4]) = wsrc[q];
    }
    __syncthreads();

    float4 pre = *reinterpret_cast<const float4*>(&hdr[256 + tx * 4]);
    float acc[4][4];
    #pragma unroll
    for (int i = 0; i < 4; ++i) {
        acc[i][0] = pre.x; acc[i][1] = pre.y; acc[i][2] = pre.z; acc[i][3] = pre.w;
    }
    #pragma unroll 8
    for (int k = 0; k < 64; ++k) {
        float4 xv = *reinterpret_cast<const float4*>(&sIE[k][ty * 4]);
        float4 wv = *reinterpret_cast<const float4*>(&sW1[k][tx * 4]);
        float xs[4] = {xv.x, xv.y, xv.z, xv.w};
        float wsv[4] = {wv.x, wv.y, wv.z, wv.w};
        #pragma unroll
        for (int i = 0; i < 4; ++i)
            #pragma unroll
            for (int j = 0; j < 4; ++j)
                acc[i][j] = fmaf(xs[i], wsv[j], acc[i][j]);
    }

    float aw[4][3];
    #pragma unroll
    for (int j = 0; j < 4; ++j) {
        aw[j][0] = aW2[(tx*4 + j)*3 + 0];
        aw[j][1] = aW2[(tx*4 + j)*3 + 1];
        aw[j][2] = aW2[(tx*4 + j)*3 + 2];
    }
    float sc[4][3];
    #pragma unroll
    for (int i = 0; i < 4; ++i) { sc[i][0] = 0.f; sc[i][1] = 0.f; sc[i][2] = 0.f; }
    #pragma unroll
    for (int i = 0; i < 4; ++i)
        #pragma unroll
        for (int j = 0; j < 4; ++j) {
            float t = tanhf(acc[i][j]);
            sc[i][0] = fmaf(t, aw[j][0], sc[i][0]);
            sc[i][1] = fmaf(t, aw[j][1], sc[i][1]);
            sc[i][2] = fmaf(t, aw[j][2], sc[i][2]);
        }
    #pragma unroll
    for (int i = 0; i < 4; ++i)
        #pragma unroll
        for (int r = 0; r < 3; ++r) {
            float v = sc[i][r];
            #pragma unroll
            for (int off = 1; off < 16; off <<= 1) v += __shfl_xor(v, off, 64);
            sc[i][r] = v;
        }

    float b20 = ab2[0], b21 = ab2[1], b22 = ab2[2];
    float4 m2v = *reinterpret_cast<const float4*>(&hdr[192 + tx * 4]);
    float m2s[4] = {m2v.x, m2v.y, m2v.z, m2v.w};

    #pragma unroll
    for (int i = 0; i < 4; ++i) {
        int row = rbase + ty * 4 + i;
        if (row >= N_ITEMS) break;
        float s0 = sc[i][0] + b20, s1 = sc[i][1] + b21, s2 = sc[i][2] + b22;
        float mx = fmaxf(s0, fmaxf(s1, s2));
        float e0w = expf(s0 - mx), e1w = expf(s1 - mx), e2w = expf(s2 - mx);
        float inv = 1.f / (e0w + e1w + e2w);
        float w0 = e0w * inv, w1 = e1w * inv, w2 = e2w * inv;

        float4 a = *reinterpret_cast<const float4*>(&m0[(size_t)row * EMB + tx * 4]);
        float4 bq = *reinterpret_cast<const float4*>(&m1[(size_t)row * EMB + tx * 4]);
        int lrow = ty * 4 + i;
        float res[4];
        #pragma unroll
        for (int j = 0; j < 4; ++j) {
            float ie = sIE[tx * 4 + j][lrow];
            float mm = (j == 0 ? a.x : j == 1 ? a.y : j == 2 ? a.z : a.w);
            float m1e = (j == 0 ? bq.x : j == 1 ? bq.y : j == 2 ? bq.z : bq.w);
            res[j] = ie + w0 * mm + w1 * m1e + w2 * m2s[j];
        }
        size_t idx = (size_t)(N_USERS + row) * EMB + tx * 4;
        *reinterpret_cast<uint2*>(&e0b[idx]) = pack4(res[0], res[1], res[2], res[3]);
    }
}

// ---------------------------------------------------------------------------
// CSR SpMM, bf16 gathers: one 64-lane wave per row, lane = dim; 8-deep
// unrolled 128B bf16 gathers (proven best depth); f32 accumulate.
// FINAL: out = (b2f(e0b) + b2f(e1b) + A*e1b) / 3.
// ---------------------------------------------------------------------------
template<int FINAL>
__global__ __launch_bounds__(256) void spmm_csr_kernel(
    const int* __restrict__ offs, const int2* __restrict__ edges,
    const unsigned short* __restrict__ srcb, const unsigned short* __restrict__ e0bm,
    float* __restrict__ outf, unsigned short* __restrict__ dstb)
{
    int r = __builtin_amdgcn_readfirstlane(blockIdx.x * 4 + (threadIdx.x >> 6));
    if (r >= N_NODES) return;
    int d = threadIdx.x & 63;
    int start = __builtin_amdgcn_readfirstlane((r == 0) ? 0 : offs[r - 1]);
    int end = __builtin_amdgcn_readfirstlane(offs[r]);
    const unsigned long long* ep = reinterpret_cast<const unsigned long long*>(edges);

    float a0 = 0.f, a1 = 0.f, a2 = 0.f, a3 = 0.f;
    int i = start;
    for (; i + 8 <= end; i += 8) {
        unsigned long long q0 = __builtin_nontemporal_load(ep + i + 0);
        unsigned long long q1 = __builtin_nontemporal_load(ep + i + 1);
        unsigned long long q2 = __builtin_nontemporal_load(ep + i + 2);
        unsigned long long q3 = __builtin_nontemporal_load(ep + i + 3);
        unsigned long long q4 = __builtin_nontemporal_load(ep + i + 4);
        unsigned long long q5 = __builtin_nontemporal_load(ep + i + 5);
        unsigned long long q6 = __builtin_nontemporal_load(ep + i + 6);
        unsigned long long q7 = __builtin_nontemporal_load(ep + i + 7);
        float x0 = b2f(srcb[(size_t)(unsigned)q0 * EMB + d]);
        float x1 = b2f(srcb[(size_t)(unsigned)q1 * EMB + d]);
        float x2 = b2f(srcb[(size_t)(unsigned)q2 * EMB + d]);
        float x3 = b2f(srcb[(size_t)(unsigned)q3 * EMB + d]);
        float x4 = b2f(srcb[(size_t)(unsigned)q4 * EMB + d]);
        float x5 = b2f(srcb[(size_t)(unsigned)q5 * EMB + d]);
        float x6 = b2f(srcb[(size_t)(unsigned)q6 * EMB + d]);
        float x7 = b2f(srcb[(size_t)(unsigned)q7 * EMB + d]);
        a0 = fmaf(__uint_as_float((unsigned)(q0 >> 32)), x0, a0);
        a1 = fmaf(__uint_as_float((unsigned)(q1 >> 32)), x1, a1);
        a2 = fmaf(__uint_as_float((unsigned)(q2 >> 32)), x2, a2);
        a3 = fmaf(__uint_as_float((unsigned)(q3 >> 32)), x3, a3);
        a0 = fmaf(__uint_as_float((unsigned)(q4 >> 32)), x4, a0);
        a1 = fmaf(__uint_as_float((unsigned)(q5 >> 32)), x5, a1);
        a2 = fmaf(__uint_as_float((unsigned)(q6 >> 32)), x6, a2);
        a3 = fmaf(__uint_as_float((unsigned)(q7 >> 32)), x7, a3);
    }
    for (; i < end; ++i) {
        unsigned long long q = __builtin_nontemporal_load(ep + i);
        float x = b2f(srcb[(size_t)(unsigned)q * EMB + d]);
        a0 = fmaf(__uint_as_float((unsigned)(q >> 32)), x, a0);
    }
    float s = (a0 + a1) + (a2 + a3);
    size_t idx = (size_t)r * EMB + d;
    if (FINAL) {
        float add = b2f(e0bm[idx]) + b2f(srcb[idx]);   // e0 + e1 (bf16 mirrors)
        __builtin_nontemporal_store((add + s) * (1.f / 3.f), &outf[idx]);
    } else {
        dstb[idx] = f2b(s);
    }
}

extern "C" void kernel_launch(void* const* d_in, const int* in_sizes, int n_in,
                              void* d_out, int out_size, void* d_ws, size_t ws_size,
                              hipStream_t stream)
{
    const float* user_emb = (const float*)d_in[0];
    const float* item_emb = (const float*)d_in[1];
    const float* mf0 = (const float*)d_in[2];
    const float* mf1 = (const float*)d_in[3];
    const float* mf2 = (const float*)d_in[4];
    const float* W0  = (const float*)d_in[5];
    const float* b0  = (const float*)d_in[6];
    const float* g0  = (const float*)d_in[7];
    const float* be0 = (const float*)d_in[8];
    const float* W1  = (const float*)d_in[9];
    const float* b1  = (const float*)d_in[10];
    const float* g1  = (const float*)d_in[11];
    const float* be1 = (const float*)d_in[12];
    const float* W2  = (const float*)d_in[13];
    const float* b2  = (const float*)d_in[14];
    const float* g2  = (const float*)d_in[15];
    const float* be2 = (const float*)d_in[16];
    const float* aW1 = (const float*)d_in[17];
    const float* ab1 = (const float*)d_in[18];
    const float* aW2 = (const float*)d_in[19];
    const float* ab2 = (const float*)d_in[20];
    const float* avals = (const float*)d_in[21];
    const int* arows = (const int*)d_in[22];
    const int* acols = (const int*)d_in[23];
    float* out = (float*)d_out;

    // layout (all dedicated, no aliasing; ~133.4 MB):
    // hdr(512f) | bktcnt(1172i) | pad | m0b | m1b | e0b | e1b | offs | edges | tmp | hmatT
    float* ws  = (float*)d_ws;
    float* hdr = ws;                                   // 512 floats
    int*   bktcnt = (int*)(ws + 512);                  // 1172 ints
    float* m0b = ws + 1792;                            // 50000*64 f32 (12.8MB)
    float* m1b = m0b + (size_t)N_ITEMS * EMB;          // 12.8MB
    unsigned short* e0b = (unsigned short*)(m1b + (size_t)N_ITEMS * EMB); // 19.2MB
    unsigned short* e1b = e0b + (size_t)N_NODES * EMB;                    // 19.2MB
    int*   offs = (int*)(e1b + (size_t)N_NODES * EMB); // 150000 ints
    int2*  edges = (int2*)(offs + N_NODES);            // 32MB
    int2*  tmp = edges + N_EDGES;                      // 32MB (dedicated)
    int*   hmatT = (int*)(tmp + N_EDGES);              // (NBKT+1)*1024 ints (4.8MB)

    hipMemsetAsync(hdr, 0, 2048 + NBKT * 4, stream);   // hdr + bktcnt

    // K1: CSR chunk-sort || enc128 colsum (Bresenham-interleaved)
    k1_kernel<<<K1_TOTAL, 256, K1_SMEM, stream>>>(
        arows, acols, avals, bktcnt, hmatT, tmp, mf2, W2, b2, g2, be2, hdr);
    // K2: gather(stage-less) || enc768 || enc384 || user_prep (interleaved)
    k2_kernel<<<K2_TOTAL, 256, K2_SMEM, stream>>>(
        tmp, hmatT, bktcnt, offs, edges,
        mf0, W0, b0, g0, be0, m0b, mf1, W1, b1, g1, be1, m1b,
        user_emb, e0b, hdr);
    finalize_kernel<<<1, 64, 0, stream>>>(aW1, ab1, hdr);
    item_fuse_gemm_kernel<<<ENC_ITEM_BLOCKS, 256, 0, stream>>>(
        item_emb, m0b, m1b, hdr, aW1, aW2, ab2, e0b);

    // two propagation layers: row-wave CSR, bf16 gathers, no atomics
    spmm_csr_kernel<0><<<(N_NODES + 3) / 4, 256, 0, stream>>>(
        offs, edges, e0b, nullptr, nullptr, e1b);
    spmm_csr_kernel<1><<<(N_NODES + 3) / 4, 256, 0, stream>>>(
        offs, edges, e1b, e0b, out, nullptr);
}

// Round 19
// 474.619 us; speedup vs baseline: 1.0216x; 1.0216x over previous
//
#include <hip/hip_runtime.h>
#include <cstdint>

#define N_USERS 100000
#define N_ITEMS 50000
#define N_NODES (N_USERS + N_ITEMS)
#define EMB 64
#define N_EDGES 4000000
#define LN_EPS 1e-5f

#define NBKT 1172           // ceil(N_NODES/128): buckets of 128 rows
#define C_BLOCKS 1024
#define EPB 3907            // ceil(N_EDGES/C_BLOCKS)
#define BCAP 4096           // per-bucket cap (mean 3413, sigma~58 -> +11s)
#define ENC128_BLOCKS 1563  // (N_USERS+63)/64
#define ENC_ITEM_BLOCKS 782 // (N_ITEMS+63)/64
#define UPREP_BLOCKS 512

#define K1_TOTAL (C_BLOCKS + ENC128_BLOCKS)                       // 2587
#define K2_OTHER (2 * ENC_ITEM_BLOCKS + UPREP_BLOCKS)             // 2076
#define K2_TOTAL (NBKT + K2_OTHER)                                // 3248

// K1 smem: stage 31264 | cnt 4688 (@31264) | offA 4704 (@35952) | sums 1024 (@40656)
#define K1_SMEM 41728
// K2 smem: stage 32768 | cnt 1024 (@32768) | pos 1024 (@33792) | sbk 1024 (@34816)
#define K2_SMEM 35840

__device__ __forceinline__ float b2f(unsigned short h) {
    return __uint_as_float((unsigned)h << 16);
}
__device__ __forceinline__ unsigned short f2b(float f) {
    unsigned u = __float_as_uint(f);
    u += 0x7FFFu + ((u >> 16) & 1u);   // RNE
    return (unsigned short)(u >> 16);
}
__device__ __forceinline__ uint2 pack4(float a, float b, float c, float d) {
    return make_uint2((unsigned)f2b(a) | ((unsigned)f2b(b) << 16),
                      (unsigned)f2b(c) | ((unsigned)f2b(d) << 16));
}

// ---------------------------------------------------------------------------
// f32 encoder body (runtime K) — R12-proven. smem carve: 8704|8192|256 = 17152
// WRITE_OUT=0: skip output, accumulate column sums into colsum[64].
// ---------------------------------------------------------------------------
template<int WRITE_OUT>
__device__ __forceinline__ void enc_body(
    int blk, char* smem, const float* __restrict__ X, const float* __restrict__ W,
    const float* __restrict__ bb, const float* __restrict__ gg,
    const float* __restrict__ be, float* __restrict__ out,
    float* __restrict__ colsum, int K, int R)
{
    float (*sXT)[68] = reinterpret_cast<float(*)[68]>(smem);
    float (*sW)[64] = reinterpret_cast<float(*)[64]>(smem + 8704);
    float* scs = reinterpret_cast<float*>(smem + 8704 + 8192);

    int tid = threadIdx.x;
    int tx = tid & 15;
    int ty = tid >> 4;
    int rbase = blk * 64;

    int xr = tid >> 2;
    int xc = (tid & 3) * 8;
    int wr = tid >> 3;
    int wc = (tid & 7) * 8;

    int gxrow = rbase + xr; if (gxrow >= R) gxrow = R - 1;
    const float* xsrc = X + (size_t)gxrow * K + xc;

    float4 bv = *reinterpret_cast<const float4*>(&bb[tx * 4]);
    float4 gv = *reinterpret_cast<const float4*>(&gg[tx * 4]);
    float4 bev = *reinterpret_cast<const float4*>(&be[tx * 4]);

    float acc[4][4];
    #pragma unroll
    for (int i = 0; i < 4; ++i) {
        acc[i][0] = bv.x; acc[i][1] = bv.y; acc[i][2] = bv.z; acc[i][3] = bv.w;
    }

    for (int kc = 0; kc < K; kc += 32) {
        float4 a0 = *reinterpret_cast<const float4*>(xsrc + kc);
        float4 a1 = *reinterpret_cast<const float4*>(xsrc + kc + 4);
        float4 w0 = *reinterpret_cast<const float4*>(&W[(size_t)(kc + wr) * EMB + wc]);
        float4 w1 = *reinterpret_cast<const float4*>(&W[(size_t)(kc + wr) * EMB + wc + 4]);
        __syncthreads();
        sXT[xc + 0][xr] = a0.x; sXT[xc + 1][xr] = a0.y;
        sXT[xc + 2][xr] = a0.z; sXT[xc + 3][xr] = a0.w;
        sXT[xc + 4][xr] = a1.x; sXT[xc + 5][xr] = a1.y;
        sXT[xc + 6][xr] = a1.z; sXT[xc + 7][xr] = a1.w;
        *reinterpret_cast<float4*>(&sW[wr][wc]) = w0;
        *reinterpret_cast<float4*>(&sW[wr][wc + 4]) = w1;
        __syncthreads();
        #pragma unroll
        for (int k = 0; k < 32; ++k) {
            float4 xv = *reinterpret_cast<const float4*>(&sXT[k][ty * 4]);
            float4 wv = *reinterpret_cast<const float4*>(&sW[k][tx * 4]);
            float xs[4] = {xv.x, xv.y, xv.z, xv.w};
            float wsv[4] = {wv.x, wv.y, wv.z, wv.w};
            #pragma unroll
            for (int i = 0; i < 4; ++i)
                #pragma unroll
                for (int j = 0; j < 4; ++j)
                    acc[i][j] = fmaf(xs[i], wsv[j], acc[i][j]);
        }
    }

    float gls[4] = {gv.x, gv.y, gv.z, gv.w};
    float bels[4] = {bev.x, bev.y, bev.z, bev.w};
    float csum[4] = {0.f, 0.f, 0.f, 0.f};
    #pragma unroll
    for (int i = 0; i < 4; ++i) {
        float s = acc[i][0] + acc[i][1] + acc[i][2] + acc[i][3];
        float q = acc[i][0]*acc[i][0] + acc[i][1]*acc[i][1]
                + acc[i][2]*acc[i][2] + acc[i][3]*acc[i][3];
        #pragma unroll
        for (int off = 1; off < 16; off <<= 1) {
            s += __shfl_xor(s, off, 64);
            q += __shfl_xor(q, off, 64);
        }
        float mu = s * (1.f / EMB);
        float var = q * (1.f / EMB) - mu * mu;
        float rs = rsqrtf(var + LN_EPS);
        int row = rbase + ty * 4 + i;
        bool valid = row < R;
        float t[4];
        #pragma unroll
        for (int j = 0; j < 4; ++j) {
            float v = (acc[i][j] - mu) * rs * gls[j] + bels[j];
            t[j] = v > 0.f ? v : 0.2f * v;
        }
        if (WRITE_OUT) {
            if (valid)
                *reinterpret_cast<float4*>(&out[(size_t)row * EMB + tx * 4]) =
                    make_float4(t[0], t[1], t[2], t[3]);
        } else {
            #pragma unroll
            for (int j = 0; j < 4; ++j) csum[j] += valid ? t[j] : 0.f;
        }
    }

    if (!WRITE_OUT) {
        #pragma unroll
        for (int j = 0; j < 4; ++j) {
            csum[j] += __shfl_xor(csum[j], 16, 64);
            csum[j] += __shfl_xor(csum[j], 32, 64);
        }
        if (tid < 64) scs[tid] = 0.f;
        __syncthreads();
        if ((tid & 63) < 16) {
            #pragma unroll
            for (int j = 0; j < 4; ++j) atomicAdd(&scs[tx * 4 + j], csum[j]);
        }
        __syncthreads();
        if (tid < 64) unsafeAtomicAdd(&colsum[tid], scs[tid]);
    }
}

// ---------------------------------------------------------------------------
// scatter_sort body: per-block LDS counting sort over 128-row buckets.
// ---------------------------------------------------------------------------
__device__ __forceinline__ void scatter_sort_body(
    int blk, char* smem, const int* __restrict__ rows,
    const int* __restrict__ cols, const float* __restrict__ vals,
    int* __restrict__ bktcnt, int* __restrict__ hmatT, int2* __restrict__ tmp)
{
    int2* stage = reinterpret_cast<int2*>(smem);
    int* cnt  = reinterpret_cast<int*>(smem + 31264);
    int* offA = reinterpret_cast<int*>(smem + 35952);
    int* sums = reinterpret_cast<int*>(smem + 40656);

    int tid = threadIdx.x;
    int s = blk * EPB;
    int e = s + EPB; if (e > N_EDGES) e = N_EDGES;
    int n = e - s;

    for (int i = tid; i < NBKT; i += 256) cnt[i] = 0;
    __syncthreads();
    for (int i = s + tid; i < e; i += 256)
        atomicAdd(&cnt[rows[i] >> 7], 1);
    __syncthreads();

    int base = tid * 5;
    int loc[5]; int run = 0;
    #pragma unroll
    for (int j = 0; j < 5; ++j) {
        int idx = base + j;
        int v = (idx < NBKT) ? cnt[idx] : 0;
        loc[j] = run; run += v;
    }
    sums[tid] = run;
    __syncthreads();
    for (int off = 1; off < 256; off <<= 1) {
        int u = (tid >= off) ? sums[tid - off] : 0;
        __syncthreads();
        sums[tid] += u;
        __syncthreads();
    }
    int excl = tid ? sums[tid - 1] : 0;
    #pragma unroll
    for (int j = 0; j < 5; ++j) {
        int idx = base + j;
        if (idx < NBKT) offA[idx] = excl + loc[j];
    }
    if (tid == 0) offA[NBKT] = n;
    __syncthreads();

    for (int i = tid; i < NBKT; i += 256) {
        if (cnt[i]) atomicAdd(&bktcnt[i], cnt[i]);
        cnt[i] = offA[i];
    }
    for (int i = tid; i <= NBKT; i += 256)
        hmatT[(size_t)i * C_BLOCKS + blk] = offA[i];
    __syncthreads();

    for (int i = s + tid; i < e; i += 256) {
        int r = rows[i];
        int p = atomicAdd(&cnt[r >> 7], 1);
        stage[p] = make_int2(cols[i] | ((r & 127) << 18), __float_as_int(vals[i]));
    }
    __syncthreads();

    int2* dst = tmp + (size_t)blk * EPB;
    for (int i = tid; i < n; i += 256) dst[i] = stage[i];
}

// ---------------------------------------------------------------------------
// gather body: bucket-per-block (128 rows); staged row-sort in LDS, coalesced
// stream to edges[]; writes offs[] (inclusive prefix).
// ---------------------------------------------------------------------------
__device__ __forceinline__ void gather_body(
    int b, char* smem, const int2* __restrict__ tmp,
    const int* __restrict__ hmatT, const int* __restrict__ bktcnt,
    int* __restrict__ offs, int2* __restrict__ edges)
{
    int2* stage = reinterpret_cast<int2*>(smem);            // 32768
    int* cnt = reinterpret_cast<int*>(smem + 32768);
    int* pos = reinterpret_cast<int*>(smem + 33792);
    int* sbk = reinterpret_cast<int*>(smem + 34816);
    int t = threadIdx.x;

    int base = t * 5, part = 0;
    #pragma unroll
    for (int j = 0; j < 5; ++j) {
        int idx = base + j;
        if (idx < b) part += bktcnt[idx];
    }
    sbk[t] = part;
    cnt[t] = 0;
    __syncthreads();
    for (int off = 1; off < 256; off <<= 1) {
        int u = (t >= off) ? sbk[t - off] : 0;
        __syncthreads();
        sbk[t] += u;
        __syncthreads();
    }
    int gb = sbk[255];

    const int* h0 = hmatT + (size_t)b * C_BLOCKS;
    const int* h1 = hmatT + (size_t)(b + 1) * C_BLOCKS;

    for (int blk = t; blk < C_BLOCKS; blk += 256) {
        int st = h0[blk], en = h1[blk];
        const int2* src = tmp + (size_t)blk * EPB;
        for (int i = st; i < en; ++i)
            atomicAdd(&cnt[(src[i].x >> 18) & 127], 1);
    }
    __syncthreads();

    int v = cnt[t];
    __syncthreads();
    for (int off = 1; off < 256; off <<= 1) {
        int u = (t >= off) ? cnt[t - off] : 0;
        __syncthreads();
        cnt[t] += u;
        __syncthreads();
    }
    int incl = cnt[t];
    int row = (b << 7) + t;
    if (t < 128 && row < N_NODES) offs[row] = gb + incl;
    pos[t] = incl - v;
    __syncthreads();
    int total = cnt[255];
    if (total > BCAP) total = BCAP;

    for (int blk = t; blk < C_BLOCKS; blk += 256) {
        int st = h0[blk], en = h1[blk];
        const int2* src = tmp + (size_t)blk * EPB;
        for (int i = st; i < en; ++i) {
            int2 ed = src[i];
            int p = atomicAdd(&pos[(ed.x >> 18) & 127], 1);
            if (p < BCAP)
                stage[p] = make_int2(ed.x & 0x3FFFF, ed.y);
        }
    }
    __syncthreads();

    for (int i = t; i < total; i += 256)
        edges[gb + i] = stage[i];
}

// ---------------------------------------------------------------------------
// user prep body: e0b (bf16 mirror only) + column-sum to hdr.
// ---------------------------------------------------------------------------
__device__ __forceinline__ void user_prep_body(
    int bid, int nblk, char* smem, const float* __restrict__ U,
    unsigned short* __restrict__ e0b, float* __restrict__ sum)
{
    float* scs = reinterpret_cast<float*>(smem);
    int tid = threadIdx.x;
    int lane = tid & 63;
    const int n4 = N_USERS * EMB / 4;
    int stride = nblk * 256;
    const float4* A = reinterpret_cast<const float4*>(U);
    uint2* OB = reinterpret_cast<uint2*>(e0b);
    float c0 = 0.f, c1 = 0.f, c2 = 0.f, c3 = 0.f;
    for (int i = bid * 256 + tid; i < n4; i += stride) {
        float4 v = A[i];
        OB[i] = pack4(v.x, v.y, v.z, v.w);
        c0 += v.x; c1 += v.y; c2 += v.z; c3 += v.w;
    }
    c0 += __shfl_xor(c0, 16, 64); c0 += __shfl_xor(c0, 32, 64);
    c1 += __shfl_xor(c1, 16, 64); c1 += __shfl_xor(c1, 32, 64);
    c2 += __shfl_xor(c2, 16, 64); c2 += __shfl_xor(c2, 32, 64);
    c3 += __shfl_xor(c3, 16, 64); c3 += __shfl_xor(c3, 32, 64);
    if (tid < 64) scs[tid] = 0.f;
    __syncthreads();
    if (lane < 16) {
        atomicAdd(&scs[lane * 4 + 0], c0);
        atomicAdd(&scs[lane * 4 + 1], c1);
        atomicAdd(&scs[lane * 4 + 2], c2);
        atomicAdd(&scs[lane * 4 + 3], c3);
    }
    __syncthreads();
    if (tid < 64) unsafeAtomicAdd(&sum[tid], scs[tid]);
}

// ---------------------------------------------------------------------------
// K1: scatter_sort || enc128-colsum, Bresenham-interleaved so each CU gets a
// mix of latency-bound (scatter) and VALU-bound (enc) blocks from the start.
// ---------------------------------------------------------------------------
__global__ __launch_bounds__(256) void k1_kernel(
    const int* __restrict__ rows, const int* __restrict__ cols,
    const float* __restrict__ vals, int* __restrict__ bktcnt,
    int* __restrict__ hmatT, int2* __restrict__ tmp,
    const float* __restrict__ mf2, const float* __restrict__ W2,
    const float* __restrict__ b2v, const float* __restrict__ g2,
    const float* __restrict__ be2, float* __restrict__ hdr)
{
    extern __shared__ char smem[];
    unsigned bid = blockIdx.x;
    unsigned c  = (bid * (unsigned)C_BLOCKS) / (unsigned)K1_TOTAL;
    unsigned c1 = ((bid + 1) * (unsigned)C_BLOCKS) / (unsigned)K1_TOTAL;
    if (c1 > c)
        scatter_sort_body((int)c, smem, rows, cols, vals, bktcnt, hmatT, tmp);
    else
        enc_body<0>((int)(bid - c), smem, mf2, W2, b2v, g2, be2,
                    nullptr, hdr + 64, 128, N_USERS);
}

// ---------------------------------------------------------------------------
// K2: gather || enc768 || enc384 || user_prep, Bresenham-interleaved.
// ---------------------------------------------------------------------------
__global__ __launch_bounds__(256) void k2_kernel(
    const int2* __restrict__ tmp, const int* __restrict__ hmatT,
    const int* __restrict__ bktcnt, int* __restrict__ offs,
    int2* __restrict__ edges,
    const float* __restrict__ mf0, const float* __restrict__ W0,
    const float* __restrict__ b0v, const float* __restrict__ g0,
    const float* __restrict__ be0, float* __restrict__ m0b,
    const float* __restrict__ mf1, const float* __restrict__ W1,
    const float* __restrict__ b1v, const float* __restrict__ g1,
    const float* __restrict__ be1, float* __restrict__ m1b,
    const float* __restrict__ U, unsigned short* __restrict__ e0b,
    float* __restrict__ hdr)
{
    extern __shared__ char smem[];
    unsigned bid = blockIdx.x;
    unsigned c  = (bid * (unsigned)NBKT) / (unsigned)K2_TOTAL;
    unsigned c1 = ((bid + 1) * (unsigned)NBKT) / (unsigned)K2_TOTAL;
    if (c1 > c) {
        gather_body((int)c, smem, tmp, hmatT, bktcnt, offs, edges);
        return;
    }
    int o = (int)(bid - c);   // 0..K2_OTHER-1
    if (o < ENC_ITEM_BLOCKS)
        enc_body<1>(o, smem, mf0, W0, b0v, g0, be0, m0b, nullptr, 768, N_ITEMS);
    else if (o < 2 * ENC_ITEM_BLOCKS)
        enc_body<1>(o - ENC_ITEM_BLOCKS, smem, mf1, W1, b1v, g1, be1,
                    m1b, nullptr, 384, N_ITEMS);
    else
        user_prep_body(o - 2 * ENC_ITEM_BLOCKS, UPREP_BLOCKS, smem, U, e0b, hdr);
}

// hdr: [0:64) u_sum [64:128) um_sum [128:192) u_mean [192:256) m2_vec [256:320) pre1
__global__ void finalize_kernel(const float* __restrict__ aW1,
                                const float* __restrict__ ab1,
                                float* __restrict__ hdr)
{
    int d = threadIdx.x; // 64 threads
    float um = hdr[d] * (1.f / N_USERS);
    float m2 = hdr[64 + d] * (1.f / N_USERS);
    hdr[128 + d] = um;
    hdr[192 + d] = m2;
    float acc = ab1[d];
    for (int k = 0; k < EMB; ++k)
        acc = fmaf(hdr[k] * (1.f / N_USERS), aW1[k * EMB + d], acc);
    hdr[256 + d] = acc;
}

// ---------------------------------------------------------------------------
// Blocked item fuse: 64 items per 256-thread block; writes e0b (bf16) only.
// ---------------------------------------------------------------------------
__global__ __launch_bounds__(256) void item_fuse_gemm_kernel(
    const float* __restrict__ item_emb, const float* __restrict__ m0,
    const float* __restrict__ m1, const float* __restrict__ hdr,
    const float* __restrict__ aW1, const float* __restrict__ aW2,
    const float* __restrict__ ab2, unsigned short* __restrict__ e0b)
{
    __shared__ float sIE[64][68];   // [k][row] transposed item tile (+4 pad)
    __shared__ float sW1[64][64];   // [k][col] = aW1[64+k][col]

    int tid = threadIdx.x;
    int tx = tid & 15;
    int ty = tid >> 4;
    int rbase = blockIdx.x * 64;

    int lr = tid >> 2;              // 0..63
    int lc = (tid & 3) * 16;        // 0,16,32,48
    int grow = rbase + lr; if (grow >= N_ITEMS) grow = N_ITEMS - 1;
    const float4* ier = reinterpret_cast<const float4*>(item_emb + (size_t)grow * EMB + lc);
    const float4* wsrc = reinterpret_cast<const float4*>(aW1 + (size_t)(64 + lr) * EMB + lc);
    #pragma unroll
    for (int q = 0; q < 4; ++q) {
        float4 v = ier[q];
        sIE[lc + q*4 + 0][lr] = v.x; sIE[lc + q*4 + 1][lr] = v.y;
        sIE[lc + q*4 + 2][lr] = v.z; sIE[lc + q*4 + 3][lr] = v.w;
        *reinterpret_cast<float4*>(&sW1[lr][lc + q*4]) = wsrc[q];
    }
    __syncthreads();

    float4 pre = *reinterpret_cast<const float4*>(&hdr[256 + tx * 4]);
    float acc[4][4];
    #pragma unroll
    for (int i = 0; i < 4; ++i) {
        acc[i][0] = pre.x; acc[i][1] = pre.y; acc[i][2] = pre.z; acc[i][3] = pre.w;
    }
    #pragma unroll 8
    for (int k = 0; k < 64; ++k) {
        float4 xv = *reinterpret_cast<const float4*>(&sIE[k][ty * 4]);
        float4 wv = *reinterpret_cast<const float4*>(&sW1[k][tx * 4]);
        float xs[4] = {xv.x, xv.y, xv.z, xv.w};
        float wsv[4] = {wv.x, wv.y, wv.z, wv.w};
        #pragma unroll
        for (int i = 0; i < 4; ++i)
            #pragma unroll
            for (int j = 0; j < 4; ++j)
                acc[i][j] = fmaf(xs[i], wsv[j], acc[i][j]);
    }

    float aw[4][3];
    #pragma unroll
    for (int j = 0; j < 4; ++j) {
        aw[j][0] = aW2[(tx*4 + j)*3 + 0];
        aw[j][1] = aW2[(tx*4 + j)*3 + 1];
        aw[j][2] = aW2[(tx*4 + j)*3 + 2];
    }
    float sc[4][3];
    #pragma unroll
    for (int i = 0; i < 4; ++i) { sc[i][0] = 0.f; sc[i][1] = 0.f; sc[i][2] = 0.f; }
    #pragma unroll
    for (int i = 0; i < 4; ++i)
        #pragma unroll
        for (int j = 0; j < 4; ++j) {
            float t = tanhf(acc[i][j]);
            sc[i][0] = fmaf(t, aw[j][0], sc[i][0]);
            sc[i][1] = fmaf(t, aw[j][1], sc[i][1]);
            sc[i][2] = fmaf(t, aw[j][2], sc[i][2]);
        }
    #pragma unroll
    for (int i = 0; i < 4; ++i)
        #pragma unroll
        for (int r = 0; r < 3; ++r) {
            float v = sc[i][r];
            #pragma unroll
            for (int off = 1; off < 16; off <<= 1) v += __shfl_xor(v, off, 64);
            sc[i][r] = v;
        }

    float b20 = ab2[0], b21 = ab2[1], b22 = ab2[2];
    float4 m2v = *reinterpret_cast<const float4*>(&hdr[192 + tx * 4]);
    float m2s[4] = {m2v.x, m2v.y, m2v.z, m2v.w};

    #pragma unroll
    for (int i = 0; i < 4; ++i) {
        int row = rbase + ty * 4 + i;
        if (row >= N_ITEMS) break;
        float s0 = sc[i][0] + b20, s1 = sc[i][1] + b21, s2 = sc[i][2] + b22;
        float mx = fmaxf(s0, fmaxf(s1, s2));
        float e0w = expf(s0 - mx), e1w = expf(s1 - mx), e2w = expf(s2 - mx);
        float inv = 1.f / (e0w + e1w + e2w);
        float w0 = e0w * inv, w1 = e1w * inv, w2 = e2w * inv;

        float4 a = *reinterpret_cast<const float4*>(&m0[(size_t)row * EMB + tx * 4]);
        float4 bq = *reinterpret_cast<const float4*>(&m1[(size_t)row * EMB + tx * 4]);
        int lrow = ty * 4 + i;
        float res[4];
        #pragma unroll
        for (int j = 0; j < 4; ++j) {
            float ie = sIE[tx * 4 + j][lrow];
            float mm = (j == 0 ? a.x : j == 1 ? a.y : j == 2 ? a.z : a.w);
            float m1e = (j == 0 ? bq.x : j == 1 ? bq.y : j == 2 ? bq.z : bq.w);
            res[j] = ie + w0 * mm + w1 * m1e + w2 * m2s[j];
        }
        size_t idx = (size_t)(N_USERS + row) * EMB + tx * 4;
        *reinterpret_cast<uint2*>(&e0b[idx]) = pack4(res[0], res[1], res[2], res[3]);
    }
}

// ---------------------------------------------------------------------------
// CSR SpMM, bf16 gathers: one 64-lane wave per row, lane = dim; 8-deep
// unrolled 128B bf16 gathers (proven best depth); f32 accumulate.
// FINAL: out = (b2f(e0b) + b2f(e1b) + A*e1b) / 3.
// ---------------------------------------------------------------------------
template<int FINAL>
__global__ __launch_bounds__(256) void spmm_csr_kernel(
    const int* __restrict__ offs, const int2* __restrict__ edges,
    const unsigned short* __restrict__ srcb, const unsigned short* __restrict__ e0bm,
    float* __restrict__ outf, unsigned short* __restrict__ dstb)
{
    int r = __builtin_amdgcn_readfirstlane(blockIdx.x * 4 + (threadIdx.x >> 6));
    if (r >= N_NODES) return;
    int d = threadIdx.x & 63;
    int start = __builtin_amdgcn_readfirstlane((r == 0) ? 0 : offs[r - 1]);
    int end = __builtin_amdgcn_readfirstlane(offs[r]);
    const unsigned long long* ep = reinterpret_cast<const unsigned long long*>(edges);

    float a0 = 0.f, a1 = 0.f, a2 = 0.f, a3 = 0.f;
    int i = start;
    for (; i + 8 <= end; i += 8) {
        unsigned long long q0 = __builtin_nontemporal_load(ep + i + 0);
        unsigned long long q1 = __builtin_nontemporal_load(ep + i + 1);
        unsigned long long q2 = __builtin_nontemporal_load(ep + i + 2);
        unsigned long long q3 = __builtin_nontemporal_load(ep + i + 3);
        unsigned long long q4 = __builtin_nontemporal_load(ep + i + 4);
        unsigned long long q5 = __builtin_nontemporal_load(ep + i + 5);
        unsigned long long q6 = __builtin_nontemporal_load(ep + i + 6);
        unsigned long long q7 = __builtin_nontemporal_load(ep + i + 7);
        float x0 = b2f(srcb[(size_t)(unsigned)q0 * EMB + d]);
        float x1 = b2f(srcb[(size_t)(unsigned)q1 * EMB + d]);
        float x2 = b2f(srcb[(size_t)(unsigned)q2 * EMB + d]);
        float x3 = b2f(srcb[(size_t)(unsigned)q3 * EMB + d]);
        float x4 = b2f(srcb[(size_t)(unsigned)q4 * EMB + d]);
        float x5 = b2f(srcb[(size_t)(unsigned)q5 * EMB + d]);
        float x6 = b2f(srcb[(size_t)(unsigned)q6 * EMB + d]);
        float x7 = b2f(srcb[(size_t)(unsigned)q7 * EMB + d]);
        a0 = fmaf(__uint_as_float((unsigned)(q0 >> 32)), x0, a0);
        a1 = fmaf(__uint_as_float((unsigned)(q1 >> 32)), x1, a1);
        a2 = fmaf(__uint_as_float((unsigned)(q2 >> 32)), x2, a2);
        a3 = fmaf(__uint_as_float((unsigned)(q3 >> 32)), x3, a3);
        a0 = fmaf(__uint_as_float((unsigned)(q4 >> 32)), x4, a0);
        a1 = fmaf(__uint_as_float((unsigned)(q5 >> 32)), x5, a1);
        a2 = fmaf(__uint_as_float((unsigned)(q6 >> 32)), x6, a2);
        a3 = fmaf(__uint_as_float((unsigned)(q7 >> 32)), x7, a3);
    }
    for (; i < end; ++i) {
        unsigned long long q = __builtin_nontemporal_load(ep + i);
        float x = b2f(srcb[(size_t)(unsigned)q * EMB + d]);
        a0 = fmaf(__uint_as_float((unsigned)(q >> 32)), x, a0);
    }
    float s = (a0 + a1) + (a2 + a3);
    size_t idx = (size_t)r * EMB + d;
    if (FINAL) {
        float add = b2f(e0bm[idx]) + b2f(srcb[idx]);   // e0 + e1 (bf16 mirrors)
        __builtin_nontemporal_store((add + s) * (1.f / 3.f), &outf[idx]);
    } else {
        dstb[idx] = f2b(s);
    }
}

extern "C" void kernel_launch(void* const* d_in, const int* in_sizes, int n_in,
                              void* d_out, int out_size, void* d_ws, size_t ws_size,
                              hipStream_t stream)
{
    const float* user_emb = (const float*)d_in[0];
    const float* item_emb = (const float*)d_in[1];
    const float* mf0 = (const float*)d_in[2];
    const float* mf1 = (const float*)d_in[3];
    const float* mf2 = (const float*)d_in[4];
    const float* W0  = (const float*)d_in[5];
    const float* b0  = (const float*)d_in[6];
    const float* g0  = (const float*)d_in[7];
    const float* be0 = (const float*)d_in[8];
    const float* W1  = (const float*)d_in[9];
    const float* b1  = (const float*)d_in[10];
    const float* g1  = (const float*)d_in[11];
    const float* be1 = (const float*)d_in[12];
    const float* W2  = (const float*)d_in[13];
    const float* b2  = (const float*)d_in[14];
    const float* g2  = (const float*)d_in[15];
    const float* be2 = (const float*)d_in[16];
    const float* aW1 = (const float*)d_in[17];
    const float* ab1 = (const float*)d_in[18];
    const float* aW2 = (const float*)d_in[19];
    const float* ab2 = (const float*)d_in[20];
    const float* avals = (const float*)d_in[21];
    const int* arows = (const int*)d_in[22];
    const int* acols = (const int*)d_in[23];
    float* out = (float*)d_out;

    // layout (all dedicated, no aliasing; ~133.4 MB):
    // hdr(512f) | bktcnt(1172i) | pad | m0b | m1b | e0b | e1b | offs | edges | tmp | hmatT
    float* ws  = (float*)d_ws;
    float* hdr = ws;                                   // 512 floats
    int*   bktcnt = (int*)(ws + 512);                  // 1172 ints
    float* m0b = ws + 1792;                            // 50000*64 f32 (12.8MB)
    float* m1b = m0b + (size_t)N_ITEMS * EMB;          // 12.8MB
    unsigned short* e0b = (unsigned short*)(m1b + (size_t)N_ITEMS * EMB); // 19.2MB
    unsigned short* e1b = e0b + (size_t)N_NODES * EMB;                    // 19.2MB
    int*   offs = (int*)(e1b + (size_t)N_NODES * EMB); // 150000 ints
    int2*  edges = (int2*)(offs + N_NODES);            // 32MB
    int2*  tmp = edges + N_EDGES;                      // 32MB (dedicated)
    int*   hmatT = (int*)(tmp + N_EDGES);              // (NBKT+1)*1024 ints (4.8MB)

    hipMemsetAsync(hdr, 0, 2048 + NBKT * 4, stream);   // hdr + bktcnt

    // K1: CSR chunk-sort || enc128 colsum (Bresenham-interleaved)
    k1_kernel<<<K1_TOTAL, 256, K1_SMEM, stream>>>(
        arows, acols, avals, bktcnt, hmatT, tmp, mf2, W2, b2, g2, be2, hdr);
    // K2: gather || enc768 || enc384 || user_prep (Bresenham-interleaved)
    k2_kernel<<<K2_TOTAL, 256, K2_SMEM, stream>>>(
        tmp, hmatT, bktcnt, offs, edges,
        mf0, W0, b0, g0, be0, m0b, mf1, W1, b1, g1, be1, m1b,
        user_emb, e0b, hdr);
    finalize_kernel<<<1, 64, 0, stream>>>(aW1, ab1, hdr);
    item_fuse_gemm_kernel<<<ENC_ITEM_BLOCKS, 256, 0, stream>>>(
        item_emb, m0b, m1b, hdr, aW1, aW2, ab2, e0b);

    // two propagation layers: row-wave CSR, bf16 gathers, no atomics
    spmm_csr_kernel<0><<<(N_NODES + 3) / 4, 256, 0, stream>>>(
        offs, edges, e0b, nullptr, nullptr, e1b);
    spmm_csr_kernel<1><<<(N_NODES + 3) / 4, 256, 0, stream>>>(
        offs, edges, e1b, e0b, out, nullptr);
}